// Round 1
// baseline (17440.433 us; speedup 1.0000x reference)
//
#include <hip/hip_runtime.h>
#include <hip/hip_cooperative_groups.h>
#include <math.h>

namespace cg = cooperative_groups;

// OSPNet: pool(2x2) -> 1x1 conv -> spatial covariance -> eigh -> log(clamp(w,1e-4))
//         -> V diag(logw) V^T -> triu flatten (*sqrt2 offdiag) -> MLP -> [32,3]
//
// R3: single cooperative mega-kernel for the whole block-Jacobi loop.
//     Previously: 105 rounds x (k_inner + k_update) = 210 serial launches
//     (~113 us/round measured vs ~25 us intrinsic work). Now: one
//     hipLaunchCooperativeKernel with grid.sync() between phases; V-init and
//     logw folded in. Update tasks repacked 16/block (4 waves x 4 passes;
//     4-aligned runs never straddle A/V-task or batch boundaries, so branches
//     and barrier counts are block-uniform). Per-task math bitwise-identical.

#define SWEEPS 7          // outer block-Jacobi sweeps (15 rounds each)
#define NROUNDS (SWEEPS * 15)

// ---- workspace layout (bytes) ----
// P [0, 79691776) dead after k_gemm_red; A/V/U/logw overlay its corpse.
#define P_OFF     0
#define A_OFF     0            // 32*256*256*4 = 8388608
#define V_OFF     8388608      // 8388608
#define U_OFF     16777216     // 32*8*1024*4 = 1048576
#define LOGW_OFF  17825792     // 32*256*4 = 32768
#define MEAN_OFF  79691776     // 32768
#define F_OFF     83558400     // 9961472 (dead after k_cov)
#define FLAT_OFF  83558400     // 4210688 (overlays f)
#define PART_OFF  93519872     // 1048576
#define H_OFF     94568448     // 32768
#define WS_REQUIRED 94601216

// round-robin tournaments
__device__ __forceinline__ void pair16(int r, int t, int& p, int& q) {
    if (t == 0) { p = 0; q = 1 + r; return; }
    int u = r + t; if (u >= 15) u -= 15;
    int v = r - t; if (v < 0) v += 15;
    p = 1 + u; q = 1 + v;
    if (p > q) { int w = p; p = q; q = w; }
}
__device__ __forceinline__ void pair32(int rr, int t, int& p, int& q) {
    if (t == 0) { p = 0; q = 1 + rr; return; }
    int u = rr + t; if (u >= 31) u -= 31;
    int v = rr - t; if (v < 0) v += 31;
    p = 1 + u; q = 1 + v;
    if (p > q) { int w = p; p = q; q = w; }
}

// ---------------- k1: 2x2 average pool
__global__ __launch_bounds__(256) void k_pool(const float* __restrict__ x, float* __restrict__ P) {
    int c = blockIdx.x, b = blockIdx.y;
    const float* xs = x + (size_t)(b * 2048 + c) * 1156;
    float* ps = P + (size_t)(b * 2048 + c) * 304;
    for (int n = threadIdx.x; n < 289; n += 256) {
        int i = n / 17, j = n % 17;
        int base = (2 * i) * 34 + 2 * j;
        ps[n] = 0.25f * (xs[base] + xs[base + 1] + xs[base + 34] + xs[base + 35]);
    }
}

// ---------------- k2: channel reduction GEMM
__global__ __launch_bounds__(256) void k_gemm_red(const float* __restrict__ P,
                                                  const float* __restrict__ Wr,
                                                  float* __restrict__ f) {
    __shared__ float Wt[32][33];
    __shared__ float Pt[32][64];
    int nt = blockIdx.x, dt = blockIdx.y, b = blockIdx.z;
    int n0 = nt * 64, d0 = dt * 32;
    int tid = threadIdx.x;
    int ty = tid >> 4, tx = tid & 15;
    float acc[2][4] = {};
    for (int c0 = 0; c0 < 2048; c0 += 32) {
        __syncthreads();
        for (int idx = tid; idx < 32 * 32; idx += 256) {
            int r = idx >> 5, cc = idx & 31;
            Wt[r][cc] = Wr[(size_t)(d0 + r) * 2048 + c0 + cc];
        }
        for (int idx = tid; idx < 32 * 64; idx += 256) {
            int r = idx >> 6, cc = idx & 63;
            int n = n0 + cc;
            Pt[r][cc] = (n < 289) ? P[(size_t)(b * 2048 + c0 + r) * 304 + n] : 0.0f;
        }
        __syncthreads();
#pragma unroll
        for (int kk = 0; kk < 32; ++kk) {
            float a0 = Wt[ty * 2 + 0][kk], a1 = Wt[ty * 2 + 1][kk];
            float p0 = Pt[kk][tx * 4 + 0], p1 = Pt[kk][tx * 4 + 1];
            float p2 = Pt[kk][tx * 4 + 2], p3 = Pt[kk][tx * 4 + 3];
            acc[0][0] += a0 * p0; acc[0][1] += a0 * p1; acc[0][2] += a0 * p2; acc[0][3] += a0 * p3;
            acc[1][0] += a1 * p0; acc[1][1] += a1 * p1; acc[1][2] += a1 * p2; acc[1][3] += a1 * p3;
        }
    }
    for (int ii = 0; ii < 2; ++ii)
        for (int jj = 0; jj < 4; ++jj) {
            int d = d0 + ty * 2 + ii, n = n0 + tx * 4 + jj;
            if (n < 289) f[(size_t)(b * 256 + d) * 304 + n] = acc[ii][jj];
        }
}

// ---------------- k3a: per-(b,d) spatial mean (fp64 accumulate)
__global__ __launch_bounds__(256) void k_mean(const float* __restrict__ f, float* __restrict__ mean) {
    int row = blockIdx.x * 4 + (threadIdx.x >> 6);
    int lane = threadIdx.x & 63;
    const float* fr = f + (size_t)row * 304;
    double s = 0.0;
    for (int n = lane; n < 289; n += 64) s += (double)fr[n];
    for (int off = 32; off; off >>= 1) s += __shfl_down(s, off);
    if (lane == 0) mean[row] = (float)(s / 289.0);
}

// ---------------- k3b: covariance (fp64 accumulate), writes FULL square A
__global__ __launch_bounds__(256) void k_cov(const float* __restrict__ f,
                                             const float* __restrict__ mean,
                                             float* __restrict__ A) {
    __shared__ float Fi[32][33];
    __shared__ float Fj[32][33];
    int b = blockIdx.x, tp = blockIdx.y;
    int ti = (int)((sqrtf(8.0f * tp + 1.0f) - 1.0f) * 0.5f);
    while (ti * (ti + 1) / 2 > tp) --ti;
    while ((ti + 1) * (ti + 2) / 2 <= tp) ++ti;
    int tj = tp - ti * (ti + 1) / 2;
    int tid = threadIdx.x;
    int tyy = tid >> 4, txx = tid & 15;
    bool diag = (ti == tj);
    double acc[2][2] = {};
    for (int nc = 0; nc < 289; nc += 32) {
        __syncthreads();
        for (int idx = tid; idx < 32 * 32; idx += 256) {
            int r = idx >> 5, k = idx & 31;
            int n = nc + k;
            int d1 = ti * 32 + r;
            Fi[r][k] = (n < 289) ? f[(size_t)(b * 256 + d1) * 304 + n] - mean[b * 256 + d1] : 0.0f;
            if (!diag) {
                int d2 = tj * 32 + r;
                Fj[r][k] = (n < 289) ? f[(size_t)(b * 256 + d2) * 304 + n] - mean[b * 256 + d2] : 0.0f;
            }
        }
        __syncthreads();
        const float(*FJ)[33] = diag ? Fi : Fj;
#pragma unroll 8
        for (int kk = 0; kk < 32; ++kk) {
            float a0 = Fi[tyy * 2 + 0][kk], a1 = Fi[tyy * 2 + 1][kk];
            float c0 = FJ[txx * 2 + 0][kk], c1 = FJ[txx * 2 + 1][kk];
            acc[0][0] += (double)a0 * c0; acc[0][1] += (double)a0 * c1;
            acc[1][0] += (double)a1 * c0; acc[1][1] += (double)a1 * c1;
        }
    }
    for (int ii = 0; ii < 2; ++ii)
        for (int jj = 0; jj < 2; ++jj) {
            int i = ti * 32 + tyy * 2 + ii, j = tj * 32 + txx * 2 + jj;
            float v = (float)(acc[ii][jj] * (1.0 / 288.0));
            A[((size_t)b << 16) + i * 256 + j] = v;
            if (!diag) A[((size_t)b << 16) + j * 256 + i] = v;
        }
}

// ---------------- R3 mega-kernel: V=I, 105 x (inner + update), logw — one launch
// grid = 256 blocks (one per (b,g)) x 256 threads; cooperative, grid.sync between phases.
__global__ __launch_bounds__(256) void k_jacobi(float* __restrict__ A,
                                                float* __restrict__ V,
                                                float* __restrict__ Ubuf,
                                                float* __restrict__ logw) {
    cg::grid_group grid = cg::this_grid();
    // inner-phase LDS
    __shared__ float S[32][33], UU[32][33];
    __shared__ float cbuf[16], sbuf[16];
    __shared__ int pbuf[16], qbuf[16];
    __shared__ float rednorm[8];
    // update-phase LDS: 4 concurrent 64-thread sub-tasks, each with its own slab
    __shared__ float U1[4][32][33], U2[4][32][33], TT[4][32][33];

    const int blk = blockIdx.x;          // 0..255
    const int b = blk >> 3, g = blk & 7; // batch, group
    const int tid = threadIdx.x;

    // ---- V = I (block owns rows g*32..g*32+31 of batch b) ----
    {
        float* Vb = V + ((size_t)b << 16) + (size_t)(g * 32) * 256;
        for (int e = tid; e < 8192; e += 256) {
            int i = e >> 8, j = e & 255;
            Vb[i * 256 + j] = ((g * 32 + i) == j) ? 1.0f : 0.0f;
        }
    }
    // No sync needed before round 0: inner reads only A (written by k_cov,
    // kernel-boundary fence); V first read in update, after grid.sync().

    for (int r = 0; r < NROUNDS; ++r) {
        const int rr = r % 15;

        // ---------- inner: this block solves 32x32 subproblem (b, g) ----------
        {
            int bp, bq; pair16(rr, g, bp, bq);
            const float* Ab = A + ((size_t)b << 16);
            for (int e = tid; e < 1024; e += 256) {
                int i = e >> 5, j = e & 31;
                int ri = (i < 16) ? bp * 16 + i : bq * 16 + i - 16;
                int rj = (j < 16) ? bp * 16 + j : bq * 16 + j - 16;
                S[i][j] = Ab[ri * 256 + rj];
                UU[i][j] = (i == j) ? 1.0f : 0.0f;
            }
            __syncthreads();
            for (int sw = 0; sw < 6; ++sw) {
                // off-diagonal norm -> adaptive early exit
                float off = 0.0f, dia = 0.0f;
                for (int e = tid; e < 1024; e += 256) {
                    int i = e >> 5, j = e & 31; float v = S[i][j];
                    if (i == j) dia += v * v; else off += v * v;
                }
                for (int o = 32; o; o >>= 1) { off += __shfl_down(off, o); dia += __shfl_down(dia, o); }
                if ((tid & 63) == 0) { rednorm[tid >> 6] = off; rednorm[4 + (tid >> 6)] = dia; }
                __syncthreads();
                off = rednorm[0] + rednorm[1] + rednorm[2] + rednorm[3];
                dia = rednorm[4] + rednorm[5] + rednorm[6] + rednorm[7];
                __syncthreads();
                if (off <= 1e-13f * fmaxf(dia, 1e-30f)) break;
                for (int rot = 0; rot < 31; ++rot) {
                    if (tid < 16) {
                        int p, q; pair32(rot, tid, p, q);
                        float app = S[p][p], aqq = S[q][q], apq = S[p][q];
                        float c = 1.0f, s = 0.0f;
                        if (apq * apq > 1e-36f) {
                            float tau = (aqq - app) / (2.0f * apq);
                            float t = 1.0f / (fabsf(tau) + sqrtf(1.0f + tau * tau));
                            if (tau < 0.0f) t = -t;
                            c = rsqrtf(1.0f + t * t); s = t * c;
                        }
                        cbuf[tid] = c; sbuf[tid] = s; pbuf[tid] = p; qbuf[tid] = q;
                    }
                    __syncthreads();
                    {   // column pass on S and U (2 pairs per thread)
                        int i = tid & 31, t0 = (tid >> 5) * 2;
#pragma unroll
                        for (int m = 0; m < 2; ++m) {
                            int t = t0 + m;
                            int p = pbuf[t], q = qbuf[t];
                            float c = cbuf[t], s = sbuf[t];
                            float x = S[i][p], y = S[i][q];
                            S[i][p] = c * x - s * y; S[i][q] = s * x + c * y;
                            x = UU[i][p]; y = UU[i][q];
                            UU[i][p] = c * x - s * y; UU[i][q] = s * x + c * y;
                        }
                    }
                    __syncthreads();
                    {   // row pass on S
                        int j = tid & 31, t0 = (tid >> 5) * 2;
#pragma unroll
                        for (int m = 0; m < 2; ++m) {
                            int t = t0 + m;
                            int p = pbuf[t], q = qbuf[t];
                            float c = cbuf[t], s = sbuf[t];
                            float x = S[p][j], y = S[q][j];
                            S[p][j] = c * x - s * y; S[q][j] = s * x + c * y;
                        }
                    }
                    __syncthreads();
                }
            }
            for (int e = tid; e < 1024; e += 256)
                Ubuf[(((size_t)b * 8 + g) << 10) + e] = UU[e >> 5][e & 31];
        }
        grid.sync();   // all U visible device-wide

        // ---------- update: 16 tasks per block = 4 waves x 4 passes ----------
        // Task run [blk*16+pass*4, +4) is 4-aligned => never straddles the
        // A-task/V-task (64) or batch (128) boundary => branch + barrier counts
        // are block-uniform per pass. Each wave owns its own LDS slab.
        {
            const int sub = tid >> 6, l = tid & 63;
            const int lr = l >> 3, lc = l & 7;
            const int a0 = lr * 4, c0 = lc * 4;
            float (*u1)[33] = U1[sub];
            float (*u2)[33] = U2[sub];
            float (*tt)[33] = TT[sub];
            for (int pass = 0; pass < 4; ++pass) {
                const int T = (blk << 4) + (pass << 2) + sub;   // 0..4095
                const int b2 = T >> 7, task = T & 127;
                if (task < 64) {
                    // A_tile <- Uk^T A_tile Ul
                    int gk = task >> 3, gl = task & 7;
                    int pk, qk, pl, ql;
                    pair16(rr, gk, pk, qk); pair16(rr, gl, pl, ql);
                    const float* Uk = Ubuf + (((size_t)b2 * 8 + gk) << 10);
                    const float* Ul = Ubuf + (((size_t)b2 * 8 + gl) << 10);
                    float* Ab = A + ((size_t)b2 << 16);
                    for (int e = l; e < 1024; e += 64) {
                        int i = e >> 5, j = e & 31;
                        u1[i][j] = Uk[e];
                        u2[i][j] = Ul[e];
                        int ri = (i < 16) ? pk * 16 + i : qk * 16 + i - 16;
                        int rj = (j < 16) ? pl * 16 + j : ql * 16 + j - 16;
                        tt[i][j] = Ab[ri * 256 + rj];
                    }
                    __syncthreads();
                    float acc[4][4] = {};
#pragma unroll 4
                    for (int k = 0; k < 32; ++k) {
                        float w0 = u1[k][a0], w1 = u1[k][a0 + 1], w2 = u1[k][a0 + 2], w3 = u1[k][a0 + 3];
                        float t0 = tt[k][c0], t1 = tt[k][c0 + 1], t2 = tt[k][c0 + 2], t3 = tt[k][c0 + 3];
                        acc[0][0] += w0 * t0; acc[0][1] += w0 * t1; acc[0][2] += w0 * t2; acc[0][3] += w0 * t3;
                        acc[1][0] += w1 * t0; acc[1][1] += w1 * t1; acc[1][2] += w1 * t2; acc[1][3] += w1 * t3;
                        acc[2][0] += w2 * t0; acc[2][1] += w2 * t1; acc[2][2] += w2 * t2; acc[2][3] += w2 * t3;
                        acc[3][0] += w3 * t0; acc[3][1] += w3 * t1; acc[3][2] += w3 * t2; acc[3][3] += w3 * t3;
                    }
                    __syncthreads();
#pragma unroll
                    for (int i = 0; i < 4; ++i)
#pragma unroll
                        for (int j = 0; j < 4; ++j) tt[a0 + i][c0 + j] = acc[i][j];
                    __syncthreads();
                    float acc2[4][4] = {};
#pragma unroll 4
                    for (int k = 0; k < 32; ++k) {
                        float w0 = tt[a0][k], w1 = tt[a0 + 1][k], w2 = tt[a0 + 2][k], w3 = tt[a0 + 3][k];
                        float u0 = u2[k][c0], u1v = u2[k][c0 + 1], u2v = u2[k][c0 + 2], u3 = u2[k][c0 + 3];
                        acc2[0][0] += w0 * u0; acc2[0][1] += w0 * u1v; acc2[0][2] += w0 * u2v; acc2[0][3] += w0 * u3;
                        acc2[1][0] += w1 * u0; acc2[1][1] += w1 * u1v; acc2[1][2] += w1 * u2v; acc2[1][3] += w1 * u3;
                        acc2[2][0] += w2 * u0; acc2[2][1] += w2 * u1v; acc2[2][2] += w2 * u2v; acc2[2][3] += w2 * u3;
                        acc2[3][0] += w3 * u0; acc2[3][1] += w3 * u1v; acc2[3][2] += w3 * u2v; acc2[3][3] += w3 * u3;
                    }
#pragma unroll
                    for (int i = 0; i < 4; ++i) {
                        int ga = a0 + i; int ri = (ga < 16) ? pk * 16 + ga : qk * 16 + ga - 16;
#pragma unroll
                        for (int j = 0; j < 4; ++j) {
                            int gc = c0 + j; int rj = (gc < 16) ? pl * 16 + gc : ql * 16 + gc - 16;
                            Ab[ri * 256 + rj] = acc2[i][j];
                        }
                    }
                } else {
                    // V <- V * Ul
                    int t2 = task - 64;
                    int rb = t2 >> 3, gl = t2 & 7;
                    int pl, ql; pair16(rr, gl, pl, ql);
                    const float* Ul = Ubuf + (((size_t)b2 * 8 + gl) << 10);
                    float* Vb = V + ((size_t)b2 << 16);
                    for (int e = l; e < 1024; e += 64) {
                        int i = e >> 5, j = e & 31;
                        u2[i][j] = Ul[e];
                        int rj = (j < 16) ? pl * 16 + j : ql * 16 + j - 16;
                        tt[i][j] = Vb[(rb * 32 + i) * 256 + rj];
                    }
                    __syncthreads();
                    float acc2[4][4] = {};
#pragma unroll 4
                    for (int k = 0; k < 32; ++k) {
                        float w0 = tt[a0][k], w1 = tt[a0 + 1][k], w2 = tt[a0 + 2][k], w3 = tt[a0 + 3][k];
                        float u0 = u2[k][c0], u1v = u2[k][c0 + 1], u2v = u2[k][c0 + 2], u3 = u2[k][c0 + 3];
                        acc2[0][0] += w0 * u0; acc2[0][1] += w0 * u1v; acc2[0][2] += w0 * u2v; acc2[0][3] += w0 * u3;
                        acc2[1][0] += w1 * u0; acc2[1][1] += w1 * u1v; acc2[1][2] += w1 * u2v; acc2[1][3] += w1 * u3;
                        acc2[2][0] += w2 * u0; acc2[2][1] += w2 * u1v; acc2[2][2] += w2 * u2v; acc2[2][3] += w2 * u3;
                        acc2[3][0] += w3 * u0; acc2[3][1] += w3 * u1v; acc2[3][2] += w3 * u2v; acc2[3][3] += w3 * u3;
                    }
#pragma unroll
                    for (int i = 0; i < 4; ++i)
#pragma unroll
                        for (int j = 0; j < 4; ++j) {
                            int gc = c0 + j; int rj = (gc < 16) ? pl * 16 + gc : ql * 16 + gc - 16;
                            Vb[(rb * 32 + a0 + i) * 256 + rj] = acc2[i][j];
                        }
                }
            }
        }
        grid.sync();   // A updates visible before next round's inner
    }

    // ---- logw = log(clamp(diag(A), 1e-4)) ----
    if (g == 0)
        logw[b * 256 + tid] = logf(fmaxf(A[((size_t)b << 16) + tid * 257], 1e-4f));
}

// ---------------- k_vlogv: L = V diag(logw) V^T, fused triu flatten (*sqrt2 offdiag)
__global__ __launch_bounds__(256) void k_vlogv(const float* __restrict__ V,
                                               const float* __restrict__ logw,
                                               float* __restrict__ flat) {
    __shared__ float Vi[32][33], Vjw[32][33];
    int t = blockIdx.x, b = blockIdx.y;
    int ti = 0;
    while (t >= 8 - ti) { t -= 8 - ti; ++ti; }
    int tj = ti + t;
    int tid = threadIdx.x;
    int ty = tid >> 4, tx = tid & 15;
    const float* Vb = V + ((size_t)b << 16);
    const float* wb = logw + b * 256;
    float acc[2][2] = {};
    for (int kc = 0; kc < 8; ++kc) {
        __syncthreads();
        for (int e = tid; e < 1024; e += 256) {
            int rr = e >> 5, cc = e & 31;
            Vi[rr][cc] = Vb[(ti * 32 + rr) * 256 + kc * 32 + cc];
            Vjw[rr][cc] = Vb[(tj * 32 + rr) * 256 + kc * 32 + cc] * wb[kc * 32 + cc];
        }
        __syncthreads();
#pragma unroll 8
        for (int k = 0; k < 32; ++k) {
            float a0 = Vi[ty * 2][k], a1 = Vi[ty * 2 + 1][k];
            float b0 = Vjw[tx * 2][k], b1 = Vjw[tx * 2 + 1][k];
            acc[0][0] += a0 * b0; acc[0][1] += a0 * b1;
            acc[1][0] += a1 * b0; acc[1][1] += a1 * b1;
        }
    }
    const float SQ2 = 1.41421356237309515f;
    float* flatb = flat + (size_t)b * 32896;
#pragma unroll
    for (int ii = 0; ii < 2; ++ii)
#pragma unroll
        for (int jj = 0; jj < 2; ++jj) {
            int gi = ti * 32 + ty * 2 + ii, gj = tj * 32 + tx * 2 + jj;
            if (gi <= gj) {
                int fidx = gi * 256 - gi * (gi - 1) / 2 + (gj - gi);
                flatb[fidx] = acc[ii][jj] * ((gi == gj) ? 1.0f : SQ2);
            }
        }
}

// ---------------- k5: MLP layer-1 partial GEMM
__global__ __launch_bounds__(256) void k_mlp1(const float* __restrict__ flat,
                                              const float* __restrict__ W1,
                                              float* __restrict__ partial) {
    __shared__ float Fl[32][65];
    __shared__ float Wl[32][65];
    int ec = blockIdx.x, jt = blockIdx.y;
    int tid = threadIdx.x;
    int e0 = ec * 1028;
    float acc[4] = {};
    for (int ch = 0; ch < 1028; ch += 64) {
        __syncthreads();
        for (int idx = tid; idx < 2048; idx += 256) {
            int row = idx >> 6, col = idx & 63;
            int e = ch + col;
            float fv = 0.0f, wv = 0.0f;
            if (e < 1028) {
                fv = flat[(size_t)row * 32896 + e0 + e];
                wv = W1[(size_t)(jt * 32 + row) * 32896 + e0 + e];
            }
            Fl[row][col] = fv; Wl[row][col] = wv;
        }
        __syncthreads();
#pragma unroll 4
        for (int ee = 0; ee < 64; ++ee) {
#pragma unroll
            for (int pp = 0; pp < 4; ++pp) {
                int pair = tid + pp * 256;
                acc[pp] += Wl[pair >> 5][ee] * Fl[pair & 31][ee];
            }
        }
    }
    for (int pp = 0; pp < 4; ++pp)
        partial[((size_t)(jt * 32 + ec) << 10) + tid + pp * 256] = acc[pp];
}

// ---------------- k6: reduce partials + bias + relu
__global__ __launch_bounds__(1024) void k_mlp1red(const float* __restrict__ partial,
                                                  const float* __restrict__ b1,
                                                  float* __restrict__ h) {
    int jt = blockIdx.x, tid = threadIdx.x;
    float acc = 0.0f;
    for (int ec = 0; ec < 32; ++ec) acc += partial[((size_t)(jt * 32 + ec) << 10) + tid];
    int j = jt * 32 + (tid >> 5), bI = tid & 31;
    h[bI * 256 + j] = fmaxf(acc + b1[j], 0.0f);
}

// ---------------- k7: final classifier
__global__ __launch_bounds__(128) void k_mlp2(const float* __restrict__ h,
                                              const float* __restrict__ W2,
                                              const float* __restrict__ b2,
                                              float* __restrict__ out) {
    int tid = threadIdx.x;
    if (tid >= 96) return;
    int bI = tid / 3, cls = tid % 3;
    double acc = (double)b2[cls];
    for (int j = 0; j < 256; ++j) acc += (double)h[bI * 256 + j] * (double)W2[cls * 256 + j];
    out[tid] = (float)acc;
}

extern "C" void kernel_launch(void* const* d_in, const int* in_sizes, int n_in,
                              void* d_out, int out_size, void* d_ws, size_t ws_size,
                              hipStream_t stream) {
    const float* x  = (const float*)d_in[0];
    const float* Wr = (const float*)d_in[1];
    const float* W1 = (const float*)d_in[2];
    const float* b1 = (const float*)d_in[3];
    const float* W2 = (const float*)d_in[4];
    const float* b2 = (const float*)d_in[5];
    float* out = (float*)d_out;
    char* ws = (char*)d_ws;
    if (ws_size < (size_t)WS_REQUIRED) return;

    float* P    = (float*)(ws + P_OFF);
    float* A    = (float*)(ws + A_OFF);
    float* V    = (float*)(ws + V_OFF);
    float* Ubuf = (float*)(ws + U_OFF);
    float* logw = (float*)(ws + LOGW_OFF);
    float* mean = (float*)(ws + MEAN_OFF);
    float* f    = (float*)(ws + F_OFF);
    float* flat = (float*)(ws + FLAT_OFF);
    float* part = (float*)(ws + PART_OFF);
    float* h    = (float*)(ws + H_OFF);

    k_pool<<<dim3(2048, 32), 256, 0, stream>>>(x, P);
    k_gemm_red<<<dim3(5, 8, 32), 256, 0, stream>>>(P, Wr, f);
    k_mean<<<2048, 256, 0, stream>>>(f, mean);
    k_cov<<<dim3(32, 36), 256, 0, stream>>>(f, mean, A);
    {
        void* args[] = { (void*)&A, (void*)&V, (void*)&Ubuf, (void*)&logw };
        hipLaunchCooperativeKernel((const void*)k_jacobi, dim3(256), dim3(256),
                                   args, 0, stream);
    }
    k_vlogv<<<dim3(36, 32), 256, 0, stream>>>(V, logw, flat);
    k_mlp1<<<dim3(32, 8), 256, 0, stream>>>(flat, W1, part);
    k_mlp1red<<<8, 1024, 0, stream>>>(part, b1, h);
    k_mlp2<<<1, 128, 0, stream>>>(h, W2, b2, out);
}

// Round 2
// 11896.927 us; speedup vs baseline: 1.4660x; 1.4660x over previous
//
#include <hip/hip_runtime.h>
#include <hip/hip_cooperative_groups.h>
#include <math.h>

namespace cg = cooperative_groups;

// OSPNet: pool(2x2) -> 1x1 conv -> spatial covariance -> eigh -> log(clamp(w,1e-4))
//         -> V diag(logw) V^T -> triu flatten (*sqrt2 offdiag) -> MLP -> [32,3]
//
// R4: mega-kernel with PER-BATCH barriers instead of grid.sync().
//     R3 post-mortem: grid.sync() ~60-70us x 210 = ~14ms of the 16.7ms kernel
//     (VALUBusy 9.3% => ~1.6ms real work). Dependencies are per-batch only
//     (batch b's update needs only batch b's 8 U's), so replace grid.sync with
//     an 8-block monotonic barrier (device-scope atomicAdd + relaxed spin +
//     acquire fence). Batches fully decoupled. blk->(b,g) remapped so a batch's
//     8 blocks share blockIdx%8 (one XCD: barrier + A/V/U stay in its 4MB L2).
//     Update repacked 2 A-passes + 2 V-passes per block (balanced 6-GEMM path).

#define SWEEPS 7          // outer block-Jacobi sweeps (15 rounds each)
#define NROUNDS (SWEEPS * 15)

// ---- workspace layout (bytes) ----
// P [0, 79691776) dead after k_gemm_red; A/V/U/logw/bar overlay its corpse.
#define P_OFF     0
#define A_OFF     0            // 32*256*256*4 = 8388608
#define V_OFF     8388608      // 8388608
#define U_OFF     16777216     // 32*8*1024*4 = 1048576
#define LOGW_OFF  17825792     // 32*256*4 = 32768
#define BAR_OFF   17858560     // 32 batches * 128B line = 4096
#define MEAN_OFF  79691776     // 32768
#define F_OFF     83558400     // 9961472 (dead after k_cov)
#define FLAT_OFF  83558400     // 4210688 (overlays f)
#define PART_OFF  93519872     // 1048576
#define H_OFF     94568448     // 32768
#define WS_REQUIRED 94601216

// round-robin tournaments
__device__ __forceinline__ void pair16(int r, int t, int& p, int& q) {
    if (t == 0) { p = 0; q = 1 + r; return; }
    int u = r + t; if (u >= 15) u -= 15;
    int v = r - t; if (v < 0) v += 15;
    p = 1 + u; q = 1 + v;
    if (p > q) { int w = p; p = q; q = w; }
}
__device__ __forceinline__ void pair32(int rr, int t, int& p, int& q) {
    if (t == 0) { p = 0; q = 1 + rr; return; }
    int u = rr + t; if (u >= 31) u -= 31;
    int v = rr - t; if (v < 0) v += 31;
    p = 1 + u; q = 1 + v;
    if (p > q) { int w = p; p = q; q = w; }
}

// per-batch monotonic barrier: 8 blocks, device-scope
__device__ __forceinline__ void batch_barrier(unsigned* __restrict__ barb,
                                              unsigned target, int tid) {
    __syncthreads();   // all waves of this block done (implies vmcnt drain)
    if (tid == 0) {
        __hip_atomic_fetch_add(barb, 1u, __ATOMIC_RELEASE, __HIP_MEMORY_SCOPE_AGENT);
        while (__hip_atomic_load(barb, __ATOMIC_RELAXED, __HIP_MEMORY_SCOPE_AGENT) < target)
            __builtin_amdgcn_s_sleep(2);
        __builtin_amdgcn_fence(__ATOMIC_ACQUIRE, "agent");
    }
    __syncthreads();
}

// ---------------- k1: 2x2 average pool
__global__ __launch_bounds__(256) void k_pool(const float* __restrict__ x, float* __restrict__ P) {
    int c = blockIdx.x, b = blockIdx.y;
    const float* xs = x + (size_t)(b * 2048 + c) * 1156;
    float* ps = P + (size_t)(b * 2048 + c) * 304;
    for (int n = threadIdx.x; n < 289; n += 256) {
        int i = n / 17, j = n % 17;
        int base = (2 * i) * 34 + 2 * j;
        ps[n] = 0.25f * (xs[base] + xs[base + 1] + xs[base + 34] + xs[base + 35]);
    }
}

// ---------------- k2: channel reduction GEMM
__global__ __launch_bounds__(256) void k_gemm_red(const float* __restrict__ P,
                                                  const float* __restrict__ Wr,
                                                  float* __restrict__ f) {
    __shared__ float Wt[32][33];
    __shared__ float Pt[32][64];
    int nt = blockIdx.x, dt = blockIdx.y, b = blockIdx.z;
    int n0 = nt * 64, d0 = dt * 32;
    int tid = threadIdx.x;
    int ty = tid >> 4, tx = tid & 15;
    float acc[2][4] = {};
    for (int c0 = 0; c0 < 2048; c0 += 32) {
        __syncthreads();
        for (int idx = tid; idx < 32 * 32; idx += 256) {
            int r = idx >> 5, cc = idx & 31;
            Wt[r][cc] = Wr[(size_t)(d0 + r) * 2048 + c0 + cc];
        }
        for (int idx = tid; idx < 32 * 64; idx += 256) {
            int r = idx >> 6, cc = idx & 63;
            int n = n0 + cc;
            Pt[r][cc] = (n < 289) ? P[(size_t)(b * 2048 + c0 + r) * 304 + n] : 0.0f;
        }
        __syncthreads();
#pragma unroll
        for (int kk = 0; kk < 32; ++kk) {
            float a0 = Wt[ty * 2 + 0][kk], a1 = Wt[ty * 2 + 1][kk];
            float p0 = Pt[kk][tx * 4 + 0], p1 = Pt[kk][tx * 4 + 1];
            float p2 = Pt[kk][tx * 4 + 2], p3 = Pt[kk][tx * 4 + 3];
            acc[0][0] += a0 * p0; acc[0][1] += a0 * p1; acc[0][2] += a0 * p2; acc[0][3] += a0 * p3;
            acc[1][0] += a1 * p0; acc[1][1] += a1 * p1; acc[1][2] += a1 * p2; acc[1][3] += a1 * p3;
        }
    }
    for (int ii = 0; ii < 2; ++ii)
        for (int jj = 0; jj < 4; ++jj) {
            int d = d0 + ty * 2 + ii, n = n0 + tx * 4 + jj;
            if (n < 289) f[(size_t)(b * 256 + d) * 304 + n] = acc[ii][jj];
        }
}

// ---------------- k3a: per-(b,d) spatial mean (fp64 accumulate)
__global__ __launch_bounds__(256) void k_mean(const float* __restrict__ f, float* __restrict__ mean) {
    int row = blockIdx.x * 4 + (threadIdx.x >> 6);
    int lane = threadIdx.x & 63;
    const float* fr = f + (size_t)row * 304;
    double s = 0.0;
    for (int n = lane; n < 289; n += 64) s += (double)fr[n];
    for (int off = 32; off; off >>= 1) s += __shfl_down(s, off);
    if (lane == 0) mean[row] = (float)(s / 289.0);
}

// ---------------- k3b: covariance (fp64 accumulate), writes FULL square A
//                   + zeroes the per-batch barrier counters
__global__ __launch_bounds__(256) void k_cov(const float* __restrict__ f,
                                             const float* __restrict__ mean,
                                             float* __restrict__ A,
                                             unsigned* __restrict__ bar) {
    __shared__ float Fi[32][33];
    __shared__ float Fj[32][33];
    int b = blockIdx.x, tp = blockIdx.y;
    if (tp == 0 && threadIdx.x == 0) bar[b * 32] = 0u;
    int ti = (int)((sqrtf(8.0f * tp + 1.0f) - 1.0f) * 0.5f);
    while (ti * (ti + 1) / 2 > tp) --ti;
    while ((ti + 1) * (ti + 2) / 2 <= tp) ++ti;
    int tj = tp - ti * (ti + 1) / 2;
    int tid = threadIdx.x;
    int tyy = tid >> 4, txx = tid & 15;
    bool diag = (ti == tj);
    double acc[2][2] = {};
    for (int nc = 0; nc < 289; nc += 32) {
        __syncthreads();
        for (int idx = tid; idx < 32 * 32; idx += 256) {
            int r = idx >> 5, k = idx & 31;
            int n = nc + k;
            int d1 = ti * 32 + r;
            Fi[r][k] = (n < 289) ? f[(size_t)(b * 256 + d1) * 304 + n] - mean[b * 256 + d1] : 0.0f;
            if (!diag) {
                int d2 = tj * 32 + r;
                Fj[r][k] = (n < 289) ? f[(size_t)(b * 256 + d2) * 304 + n] - mean[b * 256 + d2] : 0.0f;
            }
        }
        __syncthreads();
        const float(*FJ)[33] = diag ? Fi : Fj;
#pragma unroll 8
        for (int kk = 0; kk < 32; ++kk) {
            float a0 = Fi[tyy * 2 + 0][kk], a1 = Fi[tyy * 2 + 1][kk];
            float c0 = FJ[txx * 2 + 0][kk], c1 = FJ[txx * 2 + 1][kk];
            acc[0][0] += (double)a0 * c0; acc[0][1] += (double)a0 * c1;
            acc[1][0] += (double)a1 * c0; acc[1][1] += (double)a1 * c1;
        }
    }
    for (int ii = 0; ii < 2; ++ii)
        for (int jj = 0; jj < 2; ++jj) {
            int i = ti * 32 + tyy * 2 + ii, j = tj * 32 + txx * 2 + jj;
            float v = (float)(acc[ii][jj] * (1.0 / 288.0));
            A[((size_t)b << 16) + i * 256 + j] = v;
            if (!diag) A[((size_t)b << 16) + j * 256 + i] = v;
        }
}

// ---------------- R4 mega-kernel: V=I, 105 x (inner + update), logw — one launch
// 256 blocks x 256 threads; block blk: b = blk&31, g = blk>>5 (batch's 8 blocks
// share blockIdx%8 -> one XCD). Per-batch 8-block barriers, batches decoupled.
__global__ __launch_bounds__(256) void k_jacobi(float* __restrict__ A,
                                                float* __restrict__ V,
                                                float* __restrict__ Ubuf,
                                                float* __restrict__ logw,
                                                unsigned* __restrict__ bar) {
    // inner-phase LDS
    __shared__ float S[32][33], UU[32][33];
    __shared__ float cbuf[16], sbuf[16];
    __shared__ int pbuf[16], qbuf[16];
    __shared__ float rednorm[8];
    // update-phase LDS: 4 concurrent 64-thread sub-tasks, each with its own slab
    __shared__ float U1[4][32][33], U2[4][32][33], TT[4][32][33];

    const int blk = blockIdx.x;           // 0..255
    const int b = blk & 31, g = blk >> 5; // batch, group (XCD-local batches)
    const int tid = threadIdx.x;
    unsigned* barb = bar + b * 32;        // one 128B line per batch

    // ---- V = I (block owns rows g*32..g*32+31 of batch b) ----
    {
        float* Vb = V + ((size_t)b << 16) + (size_t)(g * 32) * 256;
        for (int e = tid; e < 8192; e += 256) {
            int i = e >> 8, j = e & 255;
            Vb[i * 256 + j] = ((g * 32 + i) == j) ? 1.0f : 0.0f;
        }
    }
    // No sync needed before round 0: inner reads only A (written by k_cov,
    // kernel-boundary fence); V first read in update, after barrier 1.

    for (int r = 0; r < NROUNDS; ++r) {
        const int rr = r % 15;

        // ---------- inner: this block solves 32x32 subproblem (b, g) ----------
        {
            int bp, bq; pair16(rr, g, bp, bq);
            const float* Ab = A + ((size_t)b << 16);
            for (int e = tid; e < 1024; e += 256) {
                int i = e >> 5, j = e & 31;
                int ri = (i < 16) ? bp * 16 + i : bq * 16 + i - 16;
                int rj = (j < 16) ? bp * 16 + j : bq * 16 + j - 16;
                S[i][j] = Ab[ri * 256 + rj];
                UU[i][j] = (i == j) ? 1.0f : 0.0f;
            }
            __syncthreads();
            for (int sw = 0; sw < 6; ++sw) {
                // off-diagonal norm -> adaptive early exit
                float off = 0.0f, dia = 0.0f;
                for (int e = tid; e < 1024; e += 256) {
                    int i = e >> 5, j = e & 31; float v = S[i][j];
                    if (i == j) dia += v * v; else off += v * v;
                }
                for (int o = 32; o; o >>= 1) { off += __shfl_down(off, o); dia += __shfl_down(dia, o); }
                if ((tid & 63) == 0) { rednorm[tid >> 6] = off; rednorm[4 + (tid >> 6)] = dia; }
                __syncthreads();
                off = rednorm[0] + rednorm[1] + rednorm[2] + rednorm[3];
                dia = rednorm[4] + rednorm[5] + rednorm[6] + rednorm[7];
                __syncthreads();
                if (off <= 1e-13f * fmaxf(dia, 1e-30f)) break;
                for (int rot = 0; rot < 31; ++rot) {
                    if (tid < 16) {
                        int p, q; pair32(rot, tid, p, q);
                        float app = S[p][p], aqq = S[q][q], apq = S[p][q];
                        float c = 1.0f, s = 0.0f;
                        if (apq * apq > 1e-36f) {
                            float tau = (aqq - app) / (2.0f * apq);
                            float t = 1.0f / (fabsf(tau) + sqrtf(1.0f + tau * tau));
                            if (tau < 0.0f) t = -t;
                            c = rsqrtf(1.0f + t * t); s = t * c;
                        }
                        cbuf[tid] = c; sbuf[tid] = s; pbuf[tid] = p; qbuf[tid] = q;
                    }
                    __syncthreads();
                    {   // column pass on S and U (2 pairs per thread)
                        int i = tid & 31, t0 = (tid >> 5) * 2;
#pragma unroll
                        for (int m = 0; m < 2; ++m) {
                            int t = t0 + m;
                            int p = pbuf[t], q = qbuf[t];
                            float c = cbuf[t], s = sbuf[t];
                            float x = S[i][p], y = S[i][q];
                            S[i][p] = c * x - s * y; S[i][q] = s * x + c * y;
                            x = UU[i][p]; y = UU[i][q];
                            UU[i][p] = c * x - s * y; UU[i][q] = s * x + c * y;
                        }
                    }
                    __syncthreads();
                    {   // row pass on S
                        int j = tid & 31, t0 = (tid >> 5) * 2;
#pragma unroll
                        for (int m = 0; m < 2; ++m) {
                            int t = t0 + m;
                            int p = pbuf[t], q = qbuf[t];
                            float c = cbuf[t], s = sbuf[t];
                            float x = S[p][j], y = S[q][j];
                            S[p][j] = c * x - s * y; S[q][j] = s * x + c * y;
                        }
                    }
                    __syncthreads();
                }
            }
            for (int e = tid; e < 1024; e += 256)
                Ubuf[(((size_t)b * 8 + g) << 10) + e] = UU[e >> 5][e & 31];
        }
        batch_barrier(barb, 8u * (2u * (unsigned)r + 1u), tid);   // batch's 8 U's visible

        // ---------- update: 16 tasks per block = 4 waves x 4 passes ----------
        // pass 0,1: A-tasks (2 GEMMs), pass 2,3: V-tasks (1 GEMM) — every block
        // gets 2+2, balanced 6-GEMM critical path. Runs of 4 are 4-aligned and
        // pass-type is block-uniform. Each wave owns its own LDS slab.
        {
            const int sub = tid >> 6, l = tid & 63;
            const int lr = l >> 3, lc = l & 7;
            const int a0 = lr * 4, c0 = lc * 4;
            float (*u1)[33] = U1[sub];
            float (*u2)[33] = U2[sub];
            float (*tt)[33] = TT[sub];
            for (int pass = 0; pass < 4; ++pass) {
                if (pass < 2) {
                    // A_tile <- Uk^T A_tile Ul ; task = (g*2+pass)*4 + sub in 0..63
                    const int task = (((g << 1) + pass) << 2) + sub;
                    int gk = task >> 3, gl = task & 7;
                    int pk, qk, pl, ql;
                    pair16(rr, gk, pk, qk); pair16(rr, gl, pl, ql);
                    const float* Uk = Ubuf + (((size_t)b * 8 + gk) << 10);
                    const float* Ul = Ubuf + (((size_t)b * 8 + gl) << 10);
                    float* Ab = A + ((size_t)b << 16);
                    for (int e = l; e < 1024; e += 64) {
                        int i = e >> 5, j = e & 31;
                        u1[i][j] = Uk[e];
                        u2[i][j] = Ul[e];
                        int ri = (i < 16) ? pk * 16 + i : qk * 16 + i - 16;
                        int rj = (j < 16) ? pl * 16 + j : ql * 16 + j - 16;
                        tt[i][j] = Ab[ri * 256 + rj];
                    }
                    __syncthreads();
                    float acc[4][4] = {};
#pragma unroll 4
                    for (int k = 0; k < 32; ++k) {
                        float w0 = u1[k][a0], w1 = u1[k][a0 + 1], w2 = u1[k][a0 + 2], w3 = u1[k][a0 + 3];
                        float t0 = tt[k][c0], t1 = tt[k][c0 + 1], t2 = tt[k][c0 + 2], t3 = tt[k][c0 + 3];
                        acc[0][0] += w0 * t0; acc[0][1] += w0 * t1; acc[0][2] += w0 * t2; acc[0][3] += w0 * t3;
                        acc[1][0] += w1 * t0; acc[1][1] += w1 * t1; acc[1][2] += w1 * t2; acc[1][3] += w1 * t3;
                        acc[2][0] += w2 * t0; acc[2][1] += w2 * t1; acc[2][2] += w2 * t2; acc[2][3] += w2 * t3;
                        acc[3][0] += w3 * t0; acc[3][1] += w3 * t1; acc[3][2] += w3 * t2; acc[3][3] += w3 * t3;
                    }
                    __syncthreads();
#pragma unroll
                    for (int i = 0; i < 4; ++i)
#pragma unroll
                        for (int j = 0; j < 4; ++j) tt[a0 + i][c0 + j] = acc[i][j];
                    __syncthreads();
                    float acc2[4][4] = {};
#pragma unroll 4
                    for (int k = 0; k < 32; ++k) {
                        float w0 = tt[a0][k], w1 = tt[a0 + 1][k], w2 = tt[a0 + 2][k], w3 = tt[a0 + 3][k];
                        float u0 = u2[k][c0], u1v = u2[k][c0 + 1], u2v = u2[k][c0 + 2], u3 = u2[k][c0 + 3];
                        acc2[0][0] += w0 * u0; acc2[0][1] += w0 * u1v; acc2[0][2] += w0 * u2v; acc2[0][3] += w0 * u3;
                        acc2[1][0] += w1 * u0; acc2[1][1] += w1 * u1v; acc2[1][2] += w1 * u2v; acc2[1][3] += w1 * u3;
                        acc2[2][0] += w2 * u0; acc2[2][1] += w2 * u1v; acc2[2][2] += w2 * u2v; acc2[2][3] += w2 * u3;
                        acc2[3][0] += w3 * u0; acc2[3][1] += w3 * u1v; acc2[3][2] += w3 * u2v; acc2[3][3] += w3 * u3;
                    }
#pragma unroll
                    for (int i = 0; i < 4; ++i) {
                        int ga = a0 + i; int ri = (ga < 16) ? pk * 16 + ga : qk * 16 + ga - 16;
#pragma unroll
                        for (int j = 0; j < 4; ++j) {
                            int gc = c0 + j; int rj = (gc < 16) ? pl * 16 + gc : ql * 16 + gc - 16;
                            Ab[ri * 256 + rj] = acc2[i][j];
                        }
                    }
                } else {
                    // V <- V * Ul ; t2 = (g*2+(pass-2))*4 + sub in 0..63
                    const int t2 = (((g << 1) + (pass - 2)) << 2) + sub;
                    int rb = t2 >> 3, gl = t2 & 7;
                    int pl, ql; pair16(rr, gl, pl, ql);
                    const float* Ul = Ubuf + (((size_t)b * 8 + gl) << 10);
                    float* Vb = V + ((size_t)b << 16);
                    for (int e = l; e < 1024; e += 64) {
                        int i = e >> 5, j = e & 31;
                        u2[i][j] = Ul[e];
                        int rj = (j < 16) ? pl * 16 + j : ql * 16 + j - 16;
                        tt[i][j] = Vb[(rb * 32 + i) * 256 + rj];
                    }
                    __syncthreads();
                    float acc2[4][4] = {};
#pragma unroll 4
                    for (int k = 0; k < 32; ++k) {
                        float w0 = tt[a0][k], w1 = tt[a0 + 1][k], w2 = tt[a0 + 2][k], w3 = tt[a0 + 3][k];
                        float u0 = u2[k][c0], u1v = u2[k][c0 + 1], u2v = u2[k][c0 + 2], u3 = u2[k][c0 + 3];
                        acc2[0][0] += w0 * u0; acc2[0][1] += w0 * u1v; acc2[0][2] += w0 * u2v; acc2[0][3] += w0 * u3;
                        acc2[1][0] += w1 * u0; acc2[1][1] += w1 * u1v; acc2[1][2] += w1 * u2v; acc2[1][3] += w1 * u3;
                        acc2[2][0] += w2 * u0; acc2[2][1] += w2 * u1v; acc2[2][2] += w2 * u2v; acc2[2][3] += w2 * u3;
                        acc2[3][0] += w3 * u0; acc2[3][1] += w3 * u1v; acc2[3][2] += w3 * u2v; acc2[3][3] += w3 * u3;
                    }
#pragma unroll
                    for (int i = 0; i < 4; ++i)
#pragma unroll
                        for (int j = 0; j < 4; ++j) {
                            int gc = c0 + j; int rj = (gc < 16) ? pl * 16 + gc : ql * 16 + gc - 16;
                            Vb[(rb * 32 + a0 + i) * 256 + rj] = acc2[i][j];
                        }
                }
            }
        }
        batch_barrier(barb, 8u * (2u * (unsigned)r + 2u), tid);   // A updates visible
    }

    // ---- logw = log(clamp(diag(A), 1e-4)) ----
    if (g == 0)
        logw[b * 256 + tid] = logf(fmaxf(A[((size_t)b << 16) + tid * 257], 1e-4f));
}

// ---------------- k_vlogv: L = V diag(logw) V^T, fused triu flatten (*sqrt2 offdiag)
__global__ __launch_bounds__(256) void k_vlogv(const float* __restrict__ V,
                                               const float* __restrict__ logw,
                                               float* __restrict__ flat) {
    __shared__ float Vi[32][33], Vjw[32][33];
    int t = blockIdx.x, b = blockIdx.y;
    int ti = 0;
    while (t >= 8 - ti) { t -= 8 - ti; ++ti; }
    int tj = ti + t;
    int tid = threadIdx.x;
    int ty = tid >> 4, tx = tid & 15;
    const float* Vb = V + ((size_t)b << 16);
    const float* wb = logw + b * 256;
    float acc[2][2] = {};
    for (int kc = 0; kc < 8; ++kc) {
        __syncthreads();
        for (int e = tid; e < 1024; e += 256) {
            int rr = e >> 5, cc = e & 31;
            Vi[rr][cc] = Vb[(ti * 32 + rr) * 256 + kc * 32 + cc];
            Vjw[rr][cc] = Vb[(tj * 32 + rr) * 256 + kc * 32 + cc] * wb[kc * 32 + cc];
        }
        __syncthreads();
#pragma unroll 8
        for (int k = 0; k < 32; ++k) {
            float a0 = Vi[ty * 2][k], a1 = Vi[ty * 2 + 1][k];
            float b0 = Vjw[tx * 2][k], b1 = Vjw[tx * 2 + 1][k];
            acc[0][0] += a0 * b0; acc[0][1] += a0 * b1;
            acc[1][0] += a1 * b0; acc[1][1] += a1 * b1;
        }
    }
    const float SQ2 = 1.41421356237309515f;
    float* flatb = flat + (size_t)b * 32896;
#pragma unroll
    for (int ii = 0; ii < 2; ++ii)
#pragma unroll
        for (int jj = 0; jj < 2; ++jj) {
            int gi = ti * 32 + ty * 2 + ii, gj = tj * 32 + tx * 2 + jj;
            if (gi <= gj) {
                int fidx = gi * 256 - gi * (gi - 1) / 2 + (gj - gi);
                flatb[fidx] = acc[ii][jj] * ((gi == gj) ? 1.0f : SQ2);
            }
        }
}

// ---------------- k5: MLP layer-1 partial GEMM
__global__ __launch_bounds__(256) void k_mlp1(const float* __restrict__ flat,
                                              const float* __restrict__ W1,
                                              float* __restrict__ partial) {
    __shared__ float Fl[32][65];
    __shared__ float Wl[32][65];
    int ec = blockIdx.x, jt = blockIdx.y;
    int tid = threadIdx.x;
    int e0 = ec * 1028;
    float acc[4] = {};
    for (int ch = 0; ch < 1028; ch += 64) {
        __syncthreads();
        for (int idx = tid; idx < 2048; idx += 256) {
            int row = idx >> 6, col = idx & 63;
            int e = ch + col;
            float fv = 0.0f, wv = 0.0f;
            if (e < 1028) {
                fv = flat[(size_t)row * 32896 + e0 + e];
                wv = W1[(size_t)(jt * 32 + row) * 32896 + e0 + e];
            }
            Fl[row][col] = fv; Wl[row][col] = wv;
        }
        __syncthreads();
#pragma unroll 4
        for (int ee = 0; ee < 64; ++ee) {
#pragma unroll
            for (int pp = 0; pp < 4; ++pp) {
                int pair = tid + pp * 256;
                acc[pp] += Wl[pair >> 5][ee] * Fl[pair & 31][ee];
            }
        }
    }
    for (int pp = 0; pp < 4; ++pp)
        partial[((size_t)(jt * 32 + ec) << 10) + tid + pp * 256] = acc[pp];
}

// ---------------- k6: reduce partials + bias + relu
__global__ __launch_bounds__(1024) void k_mlp1red(const float* __restrict__ partial,
                                                  const float* __restrict__ b1,
                                                  float* __restrict__ h) {
    int jt = blockIdx.x, tid = threadIdx.x;
    float acc = 0.0f;
    for (int ec = 0; ec < 32; ++ec) acc += partial[((size_t)(jt * 32 + ec) << 10) + tid];
    int j = jt * 32 + (tid >> 5), bI = tid & 31;
    h[bI * 256 + j] = fmaxf(acc + b1[j], 0.0f);
}

// ---------------- k7: final classifier
__global__ __launch_bounds__(128) void k_mlp2(const float* __restrict__ h,
                                              const float* __restrict__ W2,
                                              const float* __restrict__ b2,
                                              float* __restrict__ out) {
    int tid = threadIdx.x;
    if (tid >= 96) return;
    int bI = tid / 3, cls = tid % 3;
    double acc = (double)b2[cls];
    for (int j = 0; j < 256; ++j) acc += (double)h[bI * 256 + j] * (double)W2[cls * 256 + j];
    out[tid] = (float)acc;
}

extern "C" void kernel_launch(void* const* d_in, const int* in_sizes, int n_in,
                              void* d_out, int out_size, void* d_ws, size_t ws_size,
                              hipStream_t stream) {
    const float* x  = (const float*)d_in[0];
    const float* Wr = (const float*)d_in[1];
    const float* W1 = (const float*)d_in[2];
    const float* b1 = (const float*)d_in[3];
    const float* W2 = (const float*)d_in[4];
    const float* b2 = (const float*)d_in[5];
    float* out = (float*)d_out;
    char* ws = (char*)d_ws;
    if (ws_size < (size_t)WS_REQUIRED) return;

    float* P    = (float*)(ws + P_OFF);
    float* A    = (float*)(ws + A_OFF);
    float* V    = (float*)(ws + V_OFF);
    float* Ubuf = (float*)(ws + U_OFF);
    float* logw = (float*)(ws + LOGW_OFF);
    unsigned* bar = (unsigned*)(ws + BAR_OFF);
    float* mean = (float*)(ws + MEAN_OFF);
    float* f    = (float*)(ws + F_OFF);
    float* flat = (float*)(ws + FLAT_OFF);
    float* part = (float*)(ws + PART_OFF);
    float* h    = (float*)(ws + H_OFF);

    k_pool<<<dim3(2048, 32), 256, 0, stream>>>(x, P);
    k_gemm_red<<<dim3(5, 8, 32), 256, 0, stream>>>(P, Wr, f);
    k_mean<<<2048, 256, 0, stream>>>(f, mean);
    k_cov<<<dim3(32, 36), 256, 0, stream>>>(f, mean, A, bar);
    {
        void* args[] = { (void*)&A, (void*)&V, (void*)&Ubuf, (void*)&logw, (void*)&bar };
        hipLaunchCooperativeKernel((const void*)k_jacobi, dim3(256), dim3(256),
                                   args, 0, stream);
    }
    k_vlogv<<<dim3(36, 32), 256, 0, stream>>>(V, logw, flat);
    k_mlp1<<<dim3(32, 8), 256, 0, stream>>>(flat, W1, part);
    k_mlp1red<<<8, 1024, 0, stream>>>(part, b1, h);
    k_mlp2<<<1, 128, 0, stream>>>(h, W2, b2, out);
}